// Round 3
// baseline (47.732 us; speedup 1.0000x reference)
//
#include <hip/hip_runtime.h>

typedef __attribute__((ext_vector_type(8))) short short8;
typedef __attribute__((ext_vector_type(4))) float f32x4;
typedef unsigned int uint32;

#define QOUT 2097152

__device__ __forceinline__ unsigned short f2bf(float f){
  uint32 u = __float_as_uint(f);
  return (unsigned short)((u + 0x7FFFu + ((u >> 16) & 1u)) >> 16);
}
__device__ __forceinline__ float bf2f(unsigned short h){
  return __uint_as_float(((uint32)h) << 16);
}
__device__ __forceinline__ uint32 med3u(uint32 a, uint32 b, uint32 c){
  uint32 d;
  asm("v_med3_u32 %0, %1, %2, %3" : "=v"(d) : "v"(a), "v"(b), "v"(c));
  return d;
}
__device__ __forceinline__ void glds16(const unsigned char* g, unsigned char* l){
  __builtin_amdgcn_global_load_lds(
      (const __attribute__((address_space(1))) unsigned int*)g,
      (__attribute__((address_space(3))) unsigned int*)l, 16, 0, 0);
}

// ---------- kernel 0: split E into hi/lo bf16, swizzled half-chunk layout + norms ----------
// ebg: half-chunk hc (128 codes) at hc*32768; within: hi at cc*128, lo at 16384+cc*128;
// 8B sub-block 'sub' stored at ((sub ^ ((cc&7)<<1))<<3).
__global__ void vq_prep(const float* __restrict__ emb, unsigned char* __restrict__ ebg,
                        float* __restrict__ nrm64, int* __restrict__ cnt){
  int gt = blockIdx.x * 256 + threadIdx.x;   // 0..16383
  if (gt == 0) *cnt = 0;                     // reset last-block counter (pre-main, stream order)
  int C = gt >> 4, sub = gt & 15;
  float4 v = reinterpret_cast<const float4*>(emb)[C * 16 + sub];
  float s = v.x*v.x + v.y*v.y + v.z*v.z + v.w*v.w;
  ushort4 h, l;
  h.x = f2bf(v.x); l.x = f2bf(v.x - bf2f(h.x));
  h.y = f2bf(v.y); l.y = f2bf(v.y - bf2f(h.y));
  h.z = f2bf(v.z); l.z = f2bf(v.z - bf2f(h.z));
  h.w = f2bf(v.w); l.w = f2bf(v.w - bf2f(h.w));
  int cc = C & 127;
  int off = (C >> 7) * 32768 + cc * 128 + ((sub ^ ((cc & 7) << 1)) << 3);
  *reinterpret_cast<ushort4*>(ebg + off) = h;
  *reinterpret_cast<ushort4*>(ebg + 16384 + off) = l;
#pragma unroll
  for (int d = 1; d < 16; d <<= 1) s += __shfl_xor(s, d);
  if (sub == 0) nrm64[C] = 0.5f * s + 128.0f;
}

// ---------- kernel 1: MFMA distance + fused top-3 argmin + fused loss reduction ----------
__global__ __launch_bounds__(256, 2) void vq_main(
    const float* __restrict__ z, const float* __restrict__ emb,
    const unsigned char* __restrict__ ebg, const float* __restrict__ nrm64,
    float* __restrict__ out, float* __restrict__ partial, int* __restrict__ cnt)
{
  __shared__ __align__(16) unsigned char LB[65536];   // 2 x 32KB half-chunk buffers
  __shared__ float nrmlds[1024];
  __shared__ uint32 mg[64][2][3];
  __shared__ uint32 cand[64][4];
  __shared__ int kidx[64];
  __shared__ float werr[4];
  __shared__ float red[256];
  __shared__ int isLast;

  const int t = threadIdx.x;
  const int bi = blockIdx.x;
  const int n0 = bi * 64;
  const int b = n0 >> 10;
  const int hw0 = n0 & 1023;
  const int w = t >> 6, lane = t & 63;
  const int wm = w >> 1, wn = w & 1;
  const int l15 = lane & 15, g = lane >> 4;

  for (int i = t; i < 1024; i += 256) nrmlds[i] = nrm64[i];

  // stage z tile as zf[64][68] in buffer-1 region
  float* zf = reinterpret_cast<float*>(LB + 32768);
#pragma unroll
  for (int k = 0; k < 16; ++k){
    int li = k * 256 + t;
    int d = li >> 6, j = li & 63;
    zf[j * 68 + d] = z[((b * 64 + d) << 10) + hw0 + j];
  }
  __syncthreads();

  // issue stage of half-chunk 0 into buf0 (async; overlaps A-frag build)
#pragma unroll
  for (int r = 0; r < 8; ++r){
    int off = (r * 4 + w) * 1024;
    glds16(ebg + off + lane * 16, LB + off);
  }

  // A-fragments of (-z), hi/lo bf16. A layout: row=lane&15, k=(lane>>4)*8+j.
  short8 ah[2][2], al[2][2];
#pragma unroll
  for (int mf = 0; mf < 2; ++mf)
#pragma unroll
    for (int kf = 0; kf < 2; ++kf){
      int row = wm * 32 + mf * 16 + l15;
      int base = row * 68 + kf * 32 + g * 8;
      float4 q0 = *reinterpret_cast<float4*>(&zf[base]);
      float4 q1 = *reinterpret_cast<float4*>(&zf[base + 4]);
      float vv[8] = {q0.x,q0.y,q0.z,q0.w,q1.x,q1.y,q1.z,q1.w};
#pragma unroll
      for (int j = 0; j < 8; ++j){
        float v = -vv[j];
        unsigned short hs = f2bf(v);
        unsigned short ls = f2bf(v - bf2f(hs));
        ah[mf][kf][j] = (short)hs;
        al[mf][kf][j] = (short)ls;
      }
    }
  __syncthreads();   // drains vmcnt: buf0 ready; zf reads done -> buf1 free

  uint32 u0[8], u1[8], u2[8];
#pragma unroll
  for (int s = 0; s < 8; ++s){ u0[s] = 0xFFFFFFFFu; u1[s] = 0xFFFFFFFFu; u2[s] = 0xFFFFFFFFu; }

  const int cc0 = wn * 64 + l15;             // 2 waves split 128 codes
  const int xsw = (l15 & 7) << 1;
  const int v0s = ((g * 2) ^ xsw) << 3;
  const int v1s = ((8 + g * 2) ^ xsw) << 3;

  for (int h = 0; h < 8; ++h){
    if (h < 7){   // prefetch next half-chunk into other buffer
      const unsigned char* src = ebg + (h + 1) * 32768;
      unsigned char* dst = LB + (((h + 1) & 1) << 15);
#pragma unroll
      for (int r = 0; r < 8; ++r){
        int off = (r * 4 + w) * 1024;
        glds16(src + off + lane * 16, dst + off);
      }
    }
    const unsigned char* bufb = LB + ((h & 1) << 15);
#pragma unroll
    for (int nf = 0; nf < 4; ++nf){
      int cc = cc0 + nf * 16;
      const unsigned char* rb = bufb + cc * 128;
      short8 bh0 = *reinterpret_cast<const short8*>(rb + v0s);
      short8 bh1 = *reinterpret_cast<const short8*>(rb + v1s);
      short8 bl0 = *reinterpret_cast<const short8*>(rb + 16384 + v0s);
      short8 bl1 = *reinterpret_cast<const short8*>(rb + 16384 + v1s);
      int code = (h << 7) + cc;
      float nv = nrmlds[code];
      f32x4 a0 = {nv, nv, nv, nv};
      f32x4 a1 = {nv, nv, nv, nv};
      a0 = __builtin_amdgcn_mfma_f32_16x16x32_bf16(ah[0][0], bh0, a0, 0,0,0);
      a0 = __builtin_amdgcn_mfma_f32_16x16x32_bf16(ah[0][1], bh1, a0, 0,0,0);
      a0 = __builtin_amdgcn_mfma_f32_16x16x32_bf16(al[0][0], bh0, a0, 0,0,0);
      a0 = __builtin_amdgcn_mfma_f32_16x16x32_bf16(al[0][1], bh1, a0, 0,0,0);
      a0 = __builtin_amdgcn_mfma_f32_16x16x32_bf16(ah[0][0], bl0, a0, 0,0,0);
      a0 = __builtin_amdgcn_mfma_f32_16x16x32_bf16(ah[0][1], bl1, a0, 0,0,0);
      a1 = __builtin_amdgcn_mfma_f32_16x16x32_bf16(ah[1][0], bh0, a1, 0,0,0);
      a1 = __builtin_amdgcn_mfma_f32_16x16x32_bf16(ah[1][1], bh1, a1, 0,0,0);
      a1 = __builtin_amdgcn_mfma_f32_16x16x32_bf16(al[1][0], bh0, a1, 0,0,0);
      a1 = __builtin_amdgcn_mfma_f32_16x16x32_bf16(al[1][1], bh1, a1, 0,0,0);
      a1 = __builtin_amdgcn_mfma_f32_16x16x32_bf16(ah[1][0], bl0, a1, 0,0,0);
      a1 = __builtin_amdgcn_mfma_f32_16x16x32_bf16(ah[1][1], bl1, a1, 0,0,0);
      uint32 kb = (uint32)code;
#pragma unroll
      for (int r = 0; r < 4; ++r){
        uint32 k0v = (__float_as_uint(a0[r]) & 0xFFFFFC00u) | kb;
        u2[r] = med3u(k0v, u1[r], u2[r]);
        u1[r] = med3u(k0v, u0[r], u1[r]);
        u0[r] = u0[r] < k0v ? u0[r] : k0v;
        uint32 k1v = (__float_as_uint(a1[r]) & 0xFFFFFC00u) | kb;
        u2[4+r] = med3u(k1v, u1[4+r], u2[4+r]);
        u1[4+r] = med3u(k1v, u0[4+r], u1[4+r]);
        u0[4+r] = u0[4+r] < k1v ? u0[4+r] : k1v;
      }
    }
    __syncthreads();   // implicit vmcnt(0): prefetched half landed; all waves done reading bufb
  }

  // butterfly top-3 merge across 16 col-lanes
#pragma unroll
  for (int dm = 1; dm < 16; dm <<= 1){
#pragma unroll
    for (int s = 0; s < 8; ++s){
      uint32 x0 = (uint32)__shfl_xor((int)u0[s], dm);
      uint32 x1 = (uint32)__shfl_xor((int)u1[s], dm);
      uint32 x2 = (uint32)__shfl_xor((int)u2[s], dm);
      u2[s] = med3u(x0, u1[s], u2[s]); u1[s] = med3u(x0, u0[s], u1[s]); u0[s] = u0[s] < x0 ? u0[s] : x0;
      u2[s] = med3u(x1, u1[s], u2[s]); u1[s] = med3u(x1, u0[s], u1[s]); u0[s] = u0[s] < x1 ? u0[s] : x1;
      u2[s] = med3u(x2, u1[s], u2[s]); u1[s] = med3u(x2, u0[s], u1[s]); u0[s] = u0[s] < x2 ? u0[s] : x2;
    }
  }
  if (l15 == 0){
#pragma unroll
    for (int mf = 0; mf < 2; ++mf)
#pragma unroll
      for (int r = 0; r < 4; ++r){
        int lr = wm * 32 + mf * 16 + g * 4 + r;
        int s = mf * 4 + r;
        mg[lr][wn][0] = u0[s]; mg[lr][wn][1] = u1[s]; mg[lr][wn][2] = u2[s];
      }
  }
  __syncthreads();

  if (t < 64){
    uint32 a0k = mg[t][0][0], a1k = mg[t][0][1], a2k = mg[t][0][2];
#pragma unroll
    for (int j2 = 0; j2 < 3; ++j2){
      uint32 x = mg[t][1][j2];
      a2k = med3u(x, a1k, a2k); a1k = med3u(x, a0k, a1k); a0k = a0k < x ? a0k : x;
    }
    kidx[t] = (int)(a0k & 1023u);
    float d0 = __uint_as_float(a0k & 0xFFFFFC00u);
    float d1 = __uint_as_float(a1k & 0xFFFFFC00u);
    cand[t][0] = a0k; cand[t][1] = a1k; cand[t][2] = a2k;
    cand[t][3] = (d1 - d0 < 0.0625f) ? 1u : 0u;
  }
  __syncthreads();

  // parallel fp64 re-check of near-ties: 4 threads per row, one candidate each
  {
    int row = t >> 2, j = t & 3;
    if (cand[row][3]){
      double s = 1e300; int myk = 0x7FFFFFFF;
      if (j < 3){
        int k = (int)(cand[row][j] & 1023u);
        const float* zb = z + (b << 16) + hw0 + row;
        const float* e = emb + k * 64;
        double acc = 0.0;
        for (int d = 0; d < 64; ++d){
          double df = (double)zb[d << 10] - (double)e[d];
          acc += df * df;
        }
        s = acc; myk = k;
      }
#pragma unroll
      for (int dx = 1; dx < 4; dx <<= 1){
        double so = __shfl_xor(s, dx);
        int ko = __shfl_xor(myk, dx);
        if (so < s || (so == s && ko < myk)) { s = so; myk = ko; }
      }
      if (j == 0) kidx[row] = myk;
    }
  }
  __syncthreads();

  // epilogue: quantized write + squared error (wave-reduced) + index write
  {
    int row = t & 63, dp = t >> 6;
    int k = kidx[row];
    const float* e = emb + k * 64;
    const float* zb = z + (b << 16) + hw0 + row;
    float* ob = out + (b << 16) + hw0 + row;
    float err = 0.f;
#pragma unroll
    for (int dd = 0; dd < 16; ++dd){
      int d = dp * 16 + dd;
      float zv = zb[d << 10];
      float qv = e[d];
      ob[d << 10] = qv;
      float df = zv - qv;
      err = fmaf(df, df, err);
    }
    if (dp == 0) out[QOUT + 1 + n0 + row] = (float)k;
#pragma unroll
    for (int dx = 1; dx < 64; dx <<= 1) err += __shfl_xor(err, dx);
    if (lane == 0) werr[w] = err;
  }
  __syncthreads();
  if (t == 0){
    partial[bi] = (werr[0] + werr[1]) + (werr[2] + werr[3]);
    __threadfence();
    int pos = atomicAdd(cnt, 1);
    isLast = (pos == 511) ? 1 : 0;
  }
  __syncthreads();

  // last arriving block does the deterministic fixed-order loss reduction
  if (isLast){
    __threadfence();
    const volatile float* vp = partial;
    red[t] = vp[t] + vp[t + 256];
    __syncthreads();
    for (int ww = 128; ww > 0; ww >>= 1){
      if (t < ww) red[t] += red[t + ww];
      __syncthreads();
    }
    if (t == 0) out[QOUT] = 1.25f * red[0] * (1.0f / 2097152.0f);
  }
}

extern "C" void kernel_launch(void* const* d_in, const int* in_sizes, int n_in,
                              void* d_out, int out_size, void* d_ws, size_t ws_size,
                              hipStream_t stream) {
  const float* z   = (const float*)d_in[0];
  const float* emb = (const float*)d_in[1];
  float* out = (float*)d_out;
  unsigned char* ebg = (unsigned char*)d_ws;       // 262144 B
  float* nrm64   = (float*)(ebg + 262144);         // 1024 floats
  float* partial = nrm64 + 1024;                   // 512 floats
  int*   cnt     = (int*)(partial + 512);          // 1 int

  vq_prep <<<64,  256, 0, stream>>>(emb, ebg, nrm64, cnt);
  vq_main <<<512, 256, 0, stream>>>(z, emb, ebg, nrm64, out, partial, cnt);
}

// Round 4
// 42.882 us; speedup vs baseline: 1.1131x; 1.1131x over previous
//
#include <hip/hip_runtime.h>

typedef __attribute__((ext_vector_type(8))) short short8;
typedef __attribute__((ext_vector_type(4))) float f32x4;
typedef unsigned int uint32;

#define QOUT 2097152

__device__ __forceinline__ unsigned short f2bf(float f){
  uint32 u = __float_as_uint(f);
  return (unsigned short)((u + 0x7FFFu + ((u >> 16) & 1u)) >> 16);
}
__device__ __forceinline__ float bf2f(unsigned short h){
  return __uint_as_float(((uint32)h) << 16);
}
__device__ __forceinline__ uint32 med3u(uint32 a, uint32 b, uint32 c){
  uint32 d;
  asm("v_med3_u32 %0, %1, %2, %3" : "=v"(d) : "v"(a), "v"(b), "v"(c));
  return d;
}

// ---------- kernel 0: split E into hi/lo bf16 in FRAGMENT-LINEAR layout + norms ----------
// ebg: per 16-code group ng (0..63): 4KB block at ng*4096:
//   [kf*2048 + part*1024 + lane*16], lane = g*16 + (code&15), part: 0=hi 1=lo.
// A wave's B-fragment load is then a single contiguous 1KB global_load_dwordx4.
__global__ void vq_prep(const float* __restrict__ emb, unsigned char* __restrict__ ebg,
                        float* __restrict__ nrm64, int* __restrict__ cnt){
  int u = blockIdx.x * 256 + threadIdx.x;   // 0..8191
  if (u == 0) *cnt = 0;                     // reset last-block counter
  int C = u >> 3, oct = u & 7;              // code, dim-octet
  const float4* e4 = reinterpret_cast<const float4*>(emb) + C * 16 + oct * 2;
  float4 v0 = e4[0], v1 = e4[1];
  float vv[8] = {v0.x, v0.y, v0.z, v0.w, v1.x, v1.y, v1.z, v1.w};
  float s = 0.f;
  short8 H, L;
#pragma unroll
  for (int j = 0; j < 8; ++j){
    float v = vv[j];
    s = fmaf(v, v, s);
    unsigned short hs = f2bf(v);
    unsigned short ls = f2bf(v - bf2f(hs));
    H[j] = (short)hs; L[j] = (short)ls;
  }
  int ng = C >> 4, c15 = C & 15, kf = oct >> 2, gg = oct & 3;
  unsigned char* base = ebg + ng * 4096 + kf * 2048 + (gg * 16 + c15) * 16;
  *reinterpret_cast<short8*>(base) = H;
  *reinterpret_cast<short8*>(base + 1024) = L;
#pragma unroll
  for (int d = 1; d < 8; d <<= 1) s += __shfl_xor(s, d);
  if (oct == 0) nrm64[C] = 0.5f * s + 128.0f;
}

// ---------- kernel 1: barrier-free MFMA distance + fused top-3 argmin + loss ----------
// 512 blocks x 256 thr (4 waves). Wave (wm,wn): rows wm*32..+32, code-half wn.
__global__ __launch_bounds__(256, 2) void vq_main(
    const float* __restrict__ z, const float* __restrict__ emb,
    const unsigned char* __restrict__ ebg, const float* __restrict__ nrm64,
    float* __restrict__ out, float* __restrict__ partial, int* __restrict__ cnt)
{
  __shared__ float zf[64 * 68];     // z tile, +4 pad per row
  __shared__ float nrmlds[1024];
  __shared__ uint32 mg[64][2][3];
  __shared__ uint32 cand[64][4];
  __shared__ int kidx[64];
  __shared__ float werr[4];
  __shared__ float red[256];
  __shared__ int isLast;

  const int t = threadIdx.x;
  const int bi = blockIdx.x;
  const int n0 = bi * 64;
  const int b = n0 >> 10;
  const int hw0 = n0 & 1023;
  const int w = t >> 6, lane = t & 63;
  const int wm = w >> 1, wn = w & 1;
  const int l15 = lane & 15, g = lane >> 4;

#pragma unroll
  for (int i = 0; i < 4; ++i) nrmlds[i * 256 + t] = nrm64[i * 256 + t];

  // stage z tile: zf[j][d] = z[b, d, hw0+j]
#pragma unroll
  for (int k = 0; k < 16; ++k){
    int li = k * 256 + t;
    int d = li >> 6, j = li & 63;
    zf[j * 68 + d] = z[((b * 64 + d) << 10) + hw0 + j];
  }
  __syncthreads();

  // A-fragments of (-z), hi/lo bf16. A layout: row=lane&15, k=(lane>>4)*8+j.
  short8 ah[2][2], al[2][2];
#pragma unroll
  for (int mf = 0; mf < 2; ++mf)
#pragma unroll
    for (int kf = 0; kf < 2; ++kf){
      int row = wm * 32 + mf * 16 + l15;
      int base = row * 68 + kf * 32 + g * 8;
      float4 q0 = *reinterpret_cast<float4*>(&zf[base]);
      float4 q1 = *reinterpret_cast<float4*>(&zf[base + 4]);
      float vv[8] = {q0.x,q0.y,q0.z,q0.w,q1.x,q1.y,q1.z,q1.w};
#pragma unroll
      for (int j = 0; j < 8; ++j){
        float v = -vv[j];
        unsigned short hs = f2bf(v);
        unsigned short ls = f2bf(v - bf2f(hs));
        ah[mf][kf][j] = (short)hs;
        al[mf][kf][j] = (short)ls;
      }
    }

  uint32 u0[8], u1[8], u2[8];
#pragma unroll
  for (int s = 0; s < 8; ++s){ u0[s] = 0xFFFFFFFFu; u1[s] = 0xFFFFFFFFu; u2[s] = 0xFFFFFFFFu; }

  // main loop: 32 code-groups, direct global B-fragment loads, no barriers
  const unsigned char* pbase = ebg + (wn << 17) + (lane << 4);  // wn*32*4096
#pragma unroll
  for (int i = 0; i < 32; ++i){
    const unsigned char* p = pbase + (i << 12);
    short8 bh0 = *reinterpret_cast<const short8*>(p);
    short8 bl0 = *reinterpret_cast<const short8*>(p + 1024);
    short8 bh1 = *reinterpret_cast<const short8*>(p + 2048);
    short8 bl1 = *reinterpret_cast<const short8*>(p + 3072);
    int ng = wn * 32 + i;
    int code = (ng << 4) + l15;
    float nv = nrmlds[code];
    f32x4 a0 = {nv, nv, nv, nv};
    f32x4 a1 = {nv, nv, nv, nv};
    a0 = __builtin_amdgcn_mfma_f32_16x16x32_bf16(ah[0][0], bh0, a0, 0,0,0);
    a0 = __builtin_amdgcn_mfma_f32_16x16x32_bf16(ah[0][1], bh1, a0, 0,0,0);
    a0 = __builtin_amdgcn_mfma_f32_16x16x32_bf16(al[0][0], bh0, a0, 0,0,0);
    a0 = __builtin_amdgcn_mfma_f32_16x16x32_bf16(al[0][1], bh1, a0, 0,0,0);
    a0 = __builtin_amdgcn_mfma_f32_16x16x32_bf16(ah[0][0], bl0, a0, 0,0,0);
    a0 = __builtin_amdgcn_mfma_f32_16x16x32_bf16(ah[0][1], bl1, a0, 0,0,0);
    a1 = __builtin_amdgcn_mfma_f32_16x16x32_bf16(ah[1][0], bh0, a1, 0,0,0);
    a1 = __builtin_amdgcn_mfma_f32_16x16x32_bf16(ah[1][1], bh1, a1, 0,0,0);
    a1 = __builtin_amdgcn_mfma_f32_16x16x32_bf16(al[1][0], bh0, a1, 0,0,0);
    a1 = __builtin_amdgcn_mfma_f32_16x16x32_bf16(al[1][1], bh1, a1, 0,0,0);
    a1 = __builtin_amdgcn_mfma_f32_16x16x32_bf16(ah[1][0], bl0, a1, 0,0,0);
    a1 = __builtin_amdgcn_mfma_f32_16x16x32_bf16(ah[1][1], bl1, a1, 0,0,0);
    uint32 kb = (uint32)code;
#pragma unroll
    for (int r = 0; r < 4; ++r){
      uint32 k0v = (__float_as_uint(a0[r]) & 0xFFFFFC00u) | kb;
      u2[r] = med3u(k0v, u1[r], u2[r]);
      u1[r] = med3u(k0v, u0[r], u1[r]);
      u0[r] = u0[r] < k0v ? u0[r] : k0v;
      uint32 k1v = (__float_as_uint(a1[r]) & 0xFFFFFC00u) | kb;
      u2[4+r] = med3u(k1v, u1[4+r], u2[4+r]);
      u1[4+r] = med3u(k1v, u0[4+r], u1[4+r]);
      u0[4+r] = u0[4+r] < k1v ? u0[4+r] : k1v;
    }
  }

  // butterfly top-3 merge across the 16 col-lanes
#pragma unroll
  for (int dm = 1; dm < 16; dm <<= 1){
#pragma unroll
    for (int s = 0; s < 8; ++s){
      uint32 x0 = (uint32)__shfl_xor((int)u0[s], dm);
      uint32 x1 = (uint32)__shfl_xor((int)u1[s], dm);
      uint32 x2 = (uint32)__shfl_xor((int)u2[s], dm);
      u2[s] = med3u(x0, u1[s], u2[s]); u1[s] = med3u(x0, u0[s], u1[s]); u0[s] = u0[s] < x0 ? u0[s] : x0;
      u2[s] = med3u(x1, u1[s], u2[s]); u1[s] = med3u(x1, u0[s], u1[s]); u0[s] = u0[s] < x1 ? u0[s] : x1;
      u2[s] = med3u(x2, u1[s], u2[s]); u1[s] = med3u(x2, u0[s], u1[s]); u0[s] = u0[s] < x2 ? u0[s] : x2;
    }
  }
  if (l15 == 0){
#pragma unroll
    for (int mf = 0; mf < 2; ++mf)
#pragma unroll
      for (int r = 0; r < 4; ++r){
        int lr = wm * 32 + mf * 16 + g * 4 + r;
        int s = mf * 4 + r;
        mg[lr][wn][0] = u0[s]; mg[lr][wn][1] = u1[s]; mg[lr][wn][2] = u2[s];
      }
  }
  __syncthreads();

  if (t < 64){
    uint32 a0k = mg[t][0][0], a1k = mg[t][0][1], a2k = mg[t][0][2];
#pragma unroll
    for (int j2 = 0; j2 < 3; ++j2){
      uint32 x = mg[t][1][j2];
      a2k = med3u(x, a1k, a2k); a1k = med3u(x, a0k, a1k); a0k = a0k < x ? a0k : x;
    }
    kidx[t] = (int)(a0k & 1023u);
    float d0 = __uint_as_float(a0k & 0xFFFFFC00u);
    float d1 = __uint_as_float(a1k & 0xFFFFFC00u);
    cand[t][0] = a0k; cand[t][1] = a1k; cand[t][2] = a2k;
    cand[t][3] = (d1 - d0 < 0.0625f) ? 1u : 0u;
  }
  __syncthreads();

  // parallel fp64 re-check of near-ties: 4 threads per row (z from LDS)
  {
    int row = t >> 2, j = t & 3;
    if (cand[row][3]){
      double s = 1e300; int myk = 0x7FFFFFFF;
      if (j < 3){
        int k = (int)(cand[row][j] & 1023u);
        const float* e = emb + k * 64;
        double acc = 0.0;
        for (int d = 0; d < 64; ++d){
          double df = (double)zf[row * 68 + d] - (double)e[d];
          acc += df * df;
        }
        s = acc; myk = k;
      }
#pragma unroll
      for (int dx = 1; dx < 4; dx <<= 1){
        double so = __shfl_xor(s, dx);
        int ko = __shfl_xor(myk, dx);
        if (so < s || (so == s && ko < myk)) { s = so; myk = ko; }
      }
      if (j == 0) kidx[row] = myk;
    }
  }
  __syncthreads();

  // epilogue: quantized write + squared error (z from LDS) + index write
  {
    int row = t & 63, dp = t >> 6;
    int k = kidx[row];
    const float* e = emb + k * 64;
    float* ob = out + (b << 16) + hw0 + row;
    float err = 0.f;
#pragma unroll
    for (int dd = 0; dd < 16; ++dd){
      int d = dp * 16 + dd;
      float zv = zf[row * 68 + d];
      float qv = e[d];
      ob[d << 10] = qv;
      float df = zv - qv;
      err = fmaf(df, df, err);
    }
    if (dp == 0) out[QOUT + 1 + n0 + row] = (float)k;
#pragma unroll
    for (int dx = 1; dx < 64; dx <<= 1) err += __shfl_xor(err, dx);
    if (lane == 0) werr[w] = err;
  }
  __syncthreads();
  if (t == 0){
    partial[bi] = (werr[0] + werr[1]) + (werr[2] + werr[3]);
    __threadfence();
    int pos = atomicAdd(cnt, 1);
    isLast = (pos == 511) ? 1 : 0;
  }
  __syncthreads();

  // last arriving block: deterministic fixed-order loss reduction
  if (isLast){
    __threadfence();
    const volatile float* vp = partial;
    red[t] = vp[t] + vp[t + 256];
    __syncthreads();
    for (int ww = 128; ww > 0; ww >>= 1){
      if (t < ww) red[t] += red[t + ww];
      __syncthreads();
    }
    if (t == 0) out[QOUT] = 1.25f * red[0] * (1.0f / 2097152.0f);
  }
}

extern "C" void kernel_launch(void* const* d_in, const int* in_sizes, int n_in,
                              void* d_out, int out_size, void* d_ws, size_t ws_size,
                              hipStream_t stream) {
  const float* z   = (const float*)d_in[0];
  const float* emb = (const float*)d_in[1];
  float* out = (float*)d_out;
  unsigned char* ebg = (unsigned char*)d_ws;       // 262144 B (fragment-linear E)
  float* nrm64   = (float*)(ebg + 262144);         // 1024 floats
  float* partial = nrm64 + 1024;                   // 512 floats
  int*   cnt     = (int*)(partial + 512);          // 1 int

  vq_prep <<<32,  256, 0, stream>>>(emb, ebg, nrm64, cnt);
  vq_main <<<512, 256, 0, stream>>>(z, emb, ebg, nrm64, out, partial, cnt);
}